// Round 7
// baseline (15202.036 us; speedup 1.0000x reference)
//
#include <hip/hip_runtime.h>
#include <cstdint>
#include <cstddef>

// Problem constants (match reference)
#define B_    64
#define C_    128
#define T_    500
#define NRES  2048
#define NCLS  10

// Kernel org: 256 wgs (one per CU), 512 threads = 8 waves.
// wave wid = il (neuron). lane b: blk = b&3, bg = b>>2.
// Thread runs G2 block blk for batches 4bg..4bg+3 (4 chains in 2 v2f accs;
// element-wise IEEE RN adds — bit-exact per chain). 8 waves halves every
// per-wave LDS stream vs r6 (VALU work is layout-invariant).
// G1: wave il, lane = bat: one ascending fmaf chain per thread, in-register.
#define NWG   256
#define SL    8
#define NT    512
#define WROW  520              // skewed words per 512-block row
#define WPIT  (4 * WROW)       // words per neuron row in LDS
#define MGP   292              // maskg per-bg pitch (words), 4-aligned, mod32=4
#define XSP   132              // xs row pitch (words), 4-aligned, mod32=4

// BIT-EXACT MODEL (validated, absmax 0.0): G1: ascending fmaf chain (K=128).
// G2: KC=512 blocks [512,512,512,512], each an ascending masked rn-add chain
// starting at 0, folded left-to-right ((b0+b1)+b2)+b3.
// LIF: v = rn(rn(0.9f*v) + rn(g1+g2)). DO NOT CHANGE THE ARITHMETIC.

// r7 change vs r6 (LDS-pipe relief at constant VALU):
//  - 8 waves x 4 bats/thread: G2 weight b128s 2048->1024, G1 reads 1024->512
//    per CU per step.
//  - maskg layout [16 bg][4 blk][16 wq][4 bats] (pitch 292/72): G2 mask reads
//    16 b128/thread (was 64 b32); transpose writes <=2-way banked.
//  - xs pitch 132 (16-B aligned): G1 = 32 aligned b128 (was 128 scalar b32);
//    staging = 4 b128 writes/thread.
//  - full-64 ballot per wave; lane 0 stores one 8-B gm word (both halves).

// d_ws layout
#define WS_MASK0   0            // 16 KB: gm buf0 (4096 words: j*2+h)
#define WS_MASK1   16384        // 16 KB: gm buf1
#define WS_FLAG    32768        // 16 flags, 1024 B apart (16 KB)
#define WS_ARR     49152        // 256 arrival slots, 16 B apart (4 KB)
#define WS_WORDS   13312        // zero through 53248 B
#define NFLAG      16
#define CHKWG      (NWG - 1)

typedef float v2f __attribute__((ext_vector_type(2)));

struct SMem {
  float    WtT2[SL][WPIT];          // 66560 B : skewed W_res rows
  float    WinT2[SL][C_];           //  4096 B : W_in rows
  float    xs2[2][B_][XSP];         // 67584 B : x[:, :, t], double-buffered
  unsigned maskg[16 * MGP + 4];     // 18704 B : bat-group-major spike words
  double   clfred2[2][NCLS];        //   160 B : per-class partials, 2 bufs
};                                   // total ~157104 B => 1 wg/CU (grid = 256)

__global__ void zero_ws_kernel(unsigned* __restrict__ p, int n) {
  int i = blockIdx.x * blockDim.x + threadIdx.x;
  if (i < n) p[i] = 0u;
}

// 4-batch masked add: one weight element, 4 mask words (bats 4bg..+3).
// bfe(sign-extend) + and per bat + two <2 x float> adds (RN per elem).
#define ACC4(AA, AB, WB, MM, JB) do {                                          \
  const unsigned _k0 = (unsigned)(((int)((MM).x << (31 - (JB)))) >> 31) & (WB);\
  const unsigned _k1 = (unsigned)(((int)((MM).y << (31 - (JB)))) >> 31) & (WB);\
  const unsigned _k2 = (unsigned)(((int)((MM).z << (31 - (JB)))) >> 31) & (WB);\
  const unsigned _k3 = (unsigned)(((int)((MM).w << (31 - (JB)))) >> 31) & (WB);\
  v2f _a; _a.x = __uint_as_float(_k0); _a.y = __uint_as_float(_k1);            \
  v2f _c; _c.x = __uint_as_float(_k2); _c.y = __uint_as_float(_k3);            \
  (AA) = (AA) + _a; (AB) = (AB) + _c;                                          \
} while (0)

// one step of the 32x32 bit-matrix transpose ladder (periodic masks)
#define BT_STEP(X, D, MLO) do {                                            \
  const unsigned _y = (unsigned)__shfl_xor((int)(X), (D), 64);             \
  (X) = (b & (D)) ? (((X) & ~(MLO)) | ((_y >> (D)) & (MLO)))               \
                  : (((X) & (MLO)) | ((_y << (D)) & ~(MLO)));              \
} while (0)

#define BT_ALL(X) do {                 \
  BT_STEP(X, 16, 0x0000FFFFu);         \
  BT_STEP(X,  8, 0x00FF00FFu);         \
  BT_STEP(X,  4, 0x0F0F0F0Fu);         \
  BT_STEP(X,  2, 0x33333333u);         \
  BT_STEP(X,  1, 0x55555555u);         \
} while (0)

// exact left-to-right fold across the 4-lane block group; valid at blk==0
#define FOLD4(C) ({                                                        \
  const float _f1 = __shfl_xor((C), 1);                                    \
  const float _f2 = __shfl_xor((C), 2);                                    \
  const float _f3 = __shfl_xor((C), 3);                                    \
  __fadd_rn(__fadd_rn(__fadd_rn((C), _f1), _f2), _f3);                     \
})

__global__ void __launch_bounds__(NT, 2)
reservoir_kernel(const float* __restrict__ x, const float* __restrict__ Win,
                 const float* __restrict__ Wres, const float* __restrict__ Wclf,
                 float* __restrict__ out, unsigned char* __restrict__ ws) {
  __shared__ SMem sm;
  const int w   = blockIdx.x;
  const int tid = threadIdx.x;
  const int b   = tid & 63;          // lane index (= bat for G1/LIF)
  const int wid = tid >> 6;          // wave index 0..7 = neuron il
  const int il  = wid;
  const int blk = b & 3;             // G2: block owned by this lane
  const int bg  = b >> 2;            // G2: batch group (bats 4bg..4bg+3)
  const int iu  = __builtin_amdgcn_readfirstlane(w * SL + il);

  unsigned* gm0  = (unsigned*)(ws + WS_MASK0);
  unsigned* gm1  = (unsigned*)(ws + WS_MASK1);
  unsigned* flgb = (unsigned*)(ws + WS_FLAG);
  unsigned* arr  = (unsigned*)(ws + WS_ARR);
  unsigned* myflag = flgb + (w & (NFLAG - 1)) * 256;   // 1024-B spacing

  // ---- one-time: stage skewed W_res rows (8 float4 per thread) ----
  {
    const int j0 = tid * 32;
    #pragma unroll
    for (int r4 = 0; r4 < 8; ++r4) {
      const int j   = j0 + r4 * 4;
      const int il2 = j >> 11;
      const int pos = j & 2047;
      const int bk  = pos >> 9;
      const int s   = pos & 511;
      const float4 v4 = *(const float4*)(Wres + (size_t)(w * SL + il2) * NRES + pos);
      *(float4*)(&sm.WtT2[il2][bk * WROW + s]) = v4;
    }
  }
  {
    #pragma unroll
    for (int e = 0; e < 2; ++e) {
      const int idx = tid * 2 + e;
      sm.WinT2[idx >> 7][idx & 127] = Win[(size_t)(w * SL + (idx >> 7)) * C_ + (idx & 127)];
    }
  }

  float v = 0.f;                   // reservoir membrane (bat = lane)
  int   cntr = 0;
  double vc = 0.0;                 // classifier membrane
  int   cntc = 0;

  // prologue: stage xs(0); prefetch x(:,:,1)
  float xv[16];
  {
    const int p0 = tid * 16;
    float tmp[16];
    #pragma unroll
    for (int r = 0; r < 16; ++r) tmp[r] = x[(size_t)(p0 + r) * T_ + 0];
    #pragma unroll
    for (int q = 0; q < 4; ++q) {
      const int p = p0 + q * 4;
      float4 f4; f4.x = tmp[q*4+0]; f4.y = tmp[q*4+1]; f4.z = tmp[q*4+2]; f4.w = tmp[q*4+3];
      *(float4*)(&sm.xs2[0][p >> 7][p & 127]) = f4;
    }
    #pragma unroll
    for (int r = 0; r < 16; ++r) xv[r] = x[(size_t)(p0 + r) * T_ + 1];
  }

  for (int t = 0; t < T_; ++t) {
    unsigned* gprev = (t & 1) ? gm0 : gm1;   // s(t-1); t=0 reads zeroed gm1
    unsigned* gcur  = (t & 1) ? gm1 : gm0;

    // ---- load neuron-major ballots + bit transpose -> maskg ----
    // wave wid: cols k = wid*8..+7. lane (hh=b>>5, i32=b&31) loads
    // gm[(k*32+i32)*2+hh]; after BT_ALL lane b holds the word for bat b.
    {
      const int i32 = b & 31, hh = b >> 5;
      #pragma unroll
      for (int kk = 0; kk < 8; ++kk) {
        const int k = (wid << 3) | kk;
        unsigned xw = __hip_atomic_load(gprev + (k * 32 + i32) * 2 + hh,
                                        __ATOMIC_RELAXED, __HIP_MEMORY_SCOPE_AGENT);
        BT_ALL(xw);
        sm.maskg[(b >> 2) * MGP + (k >> 4) * 72 + (k & 15) * 4 + (b & 3)] = xw;
      }
    }
    __syncthreads();  // A: maskg + xs(t) ready (also guards one-time stages)

    // ---- stage xs(t+1); prefetch x(:,:,t+2) ----
    if (t + 1 < T_) {
      const int p0 = tid * 16;
      #pragma unroll
      for (int q = 0; q < 4; ++q) {
        const int p = p0 + q * 4;
        float4 f4; f4.x = xv[q*4+0]; f4.y = xv[q*4+1]; f4.z = xv[q*4+2]; f4.w = xv[q*4+3];
        *(float4*)(&sm.xs2[(t + 1) & 1][p >> 7][p & 127]) = f4;
      }
      if (t + 2 < T_) {
        #pragma unroll
        for (int r = 0; r < 16; ++r) xv[r] = x[(size_t)(p0 + r) * T_ + (t + 2)];
      }
    }

    // ---- G1 (lane = bat): ascending fmaf chain over c = 0..127 ----
    float g1 = 0.f;
    {
      const float4* __restrict__ winp = (const float4*)&sm.WinT2[il][0];
      const float4* __restrict__ xrp  = (const float4*)&sm.xs2[t & 1][b][0];
      #pragma unroll 8
      for (int cq = 0; cq < 32; ++cq) {
        const float4 wv = winp[cq];
        const float4 xq = xrp[cq];
        g1 = fmaf(xq.x, wv.x, g1);
        g1 = fmaf(xq.y, wv.y, g1);
        g1 = fmaf(xq.z, wv.z, g1);
        g1 = fmaf(xq.w, wv.w, g1);
      }
    }

    // ---- G2: block blk for bats 4bg..4bg+3 (4 chains, 2 v2f accs) ----
    v2f accA; accA.x = 0.f; accA.y = 0.f;   // bats 4bg+0, 4bg+1
    v2f accB; accB.x = 0.f; accB.y = 0.f;   // bats 4bg+2, 4bg+3
    {
      const float*    wbase = &sm.WtT2[il][blk * WROW];
      const unsigned* mgb   = &sm.maskg[bg * MGP + blk * 72];
      for (int wq = 0; wq < 16; ++wq) {
        const uint4 mm = *(const uint4*)(mgb + wq * 4);
        const float4* q = (const float4*)(wbase + wq * 32);
        #pragma unroll
        for (int jq = 0; jq < 8; ++jq) {
          const float4 w4 = q[jq];
          const int jb = jq * 4;
          ACC4(accA, accB, __float_as_uint(w4.x), mm, jb + 0);
          ACC4(accA, accB, __float_as_uint(w4.y), mm, jb + 1);
          ACC4(accA, accB, __float_as_uint(w4.z), mm, jb + 2);
          ACC4(accA, accB, __float_as_uint(w4.w), mm, jb + 3);
        }
      }
    }

    // ---- fold ((b0+b1)+b2)+b3 (valid at blk0 lane), redistribute ----
    {
      const float f0 = FOLD4(accA.x);
      const float f1 = FOLD4(accA.y);
      const float f2 = FOLD4(accB.x);
      const float f3 = FOLD4(accB.y);
      const int src = b & ~3;                // blk0 lane of my group
      const float r0 = __shfl(f0, src, 64);
      const float r1 = __shfl(f1, src, 64);
      const float r2 = __shfl(f2, src, 64);
      const float r3 = __shfl(f3, src, 64);
      const int j2 = b & 3;
      const float sA = (j2 & 1) ? r1 : r0;
      const float sB = (j2 & 1) ? r3 : r2;
      const float g2m = (j2 & 2) ? sB : sA;

      // ---- LIF (lane = bat), full-wave ballot, one 8-B gm store ----
      const float I = __fadd_rn(g1, g2m);
      v = __fadd_rn(__fmul_rn(0.9f, v), I);
      const bool s = (v >= 1.0f);
      if (s) { v = 0.f; cntr++; }
      const unsigned long long bal = __ballot(s);  // bit b = spike(bat b, iu)
      if (b == 0)
        __hip_atomic_store((unsigned long long*)gcur + iu, bal,
                           __ATOMIC_RELAXED, __HIP_MEMORY_SCOPE_AGENT);
    }
    __syncthreads();  // B: all waves' gm stores drained before arrival

    // ---- FLAT ARRIVAL: own slot, release store (orders the gm stores) ----
    if (tid == 0)
      __hip_atomic_store(arr + w * 4, (unsigned)(t + 1),
                         __ATOMIC_RELEASE, __HIP_MEMORY_SCOPE_AGENT);

    // ---- CHECKER (wg 255, wave 0): poll all 256 slots, then release ----
    if (w == CHKWG && wid == 0) {
      const unsigned tgt = (unsigned)(t + 1);
      for (;;) {
        unsigned a0 = __hip_atomic_load(arr + (b +   0) * 4, __ATOMIC_RELAXED,
                                        __HIP_MEMORY_SCOPE_AGENT);
        unsigned a1 = __hip_atomic_load(arr + (b +  64) * 4, __ATOMIC_RELAXED,
                                        __HIP_MEMORY_SCOPE_AGENT);
        unsigned a2 = __hip_atomic_load(arr + (b + 128) * 4, __ATOMIC_RELAXED,
                                        __HIP_MEMORY_SCOPE_AGENT);
        unsigned a3 = __hip_atomic_load(arr + (b + 192) * 4, __ATOMIC_RELAXED,
                                        __HIP_MEMORY_SCOPE_AGENT);
        bool ok = (a0 >= tgt) & (a1 >= tgt) & (a2 >= tgt) & (a3 >= tgt);
        if (__all(ok)) break;
        __builtin_amdgcn_s_sleep(1);
      }
      if (b < NFLAG)
        __hip_atomic_store(flgb + b * 256, (unsigned)(t + 1),
                           __ATOMIC_RELEASE, __HIP_MEMORY_SCOPE_AGENT);
    }

    // ---- classifier partials for s(t-1): wg w<64, classes wid, wid+8 ----
    if (w < B_) {
      for (int c = wid; c < NCLS; c += 8) {
        double pc = 0.0;
        if (t > 0) {
          const float* __restrict__ wc = Wclf + (size_t)c * NRES + b;
          #pragma unroll 4
          for (int q = 0; q < 32; ++q) {
            const int W = 2 * q + (b >> 5);
            const unsigned mw =
                sm.maskg[(w >> 2) * MGP + (W >> 4) * 72 + (W & 15) * 4 + (w & 3)];
            const float wv = wc[q * 64];
            const unsigned keep =
                (unsigned)(((int)(mw << (31 - (b & 31)))) >> 31);
            pc += (double)__uint_as_float(keep & __float_as_uint(wv));
          }
        }
        #pragma unroll
        for (int off = 1; off < 64; off <<= 1)
          pc += __shfl_xor(pc, off, 64);
        if (b == 0) sm.clfred2[t & 1][c] = pc;
      }
    }

    // ---- classifier LIF: consume PREV step's partial (single value) ----
    if (w < B_ && tid < NCLS && t >= 2) {
      vc = 0.9 * vc + sm.clfred2[(t + 1) & 1][tid];
      if (vc >= 1.0) { vc = 0.0; cntc++; }
    }

    // ---- poll this wg's release flag ----
    if (tid == 0) {
      while (__hip_atomic_load(myflag, __ATOMIC_RELAXED,
                               __HIP_MEMORY_SCOPE_AGENT) < (unsigned)(t + 1))
        __builtin_amdgcn_s_sleep(1);
    }
    __syncthreads();  // D: whole wg proceeds past the grid barrier
  }

  // ======== epilogue ========
  // E1: deferred consume of partials written at t=499 (s(498), buf 1)
  if (w < B_ && tid < NCLS) {
    vc = 0.9 * vc + sm.clfred2[1][tid];
    if (vc >= 1.0) { vc = 0.0; cntc++; }
  }
  // E2: transpose s(499) (in gm1 since 499&1==1) -> maskg
  {
    const int i32 = b & 31, hh = b >> 5;
    #pragma unroll
    for (int kk = 0; kk < 8; ++kk) {
      const int k = (wid << 3) | kk;
      unsigned xw = __hip_atomic_load(gm1 + (k * 32 + i32) * 2 + hh,
                                      __ATOMIC_RELAXED, __HIP_MEMORY_SCOPE_AGENT);
      BT_ALL(xw);
      sm.maskg[(b >> 2) * MGP + (k >> 4) * 72 + (k & 15) * 4 + (b & 3)] = xw;
    }
  }
  __syncthreads();
  // E3: classifier partials for s(499) -> clfred2[0]
  if (w < B_) {
    for (int c = wid; c < NCLS; c += 8) {
      double pc = 0.0;
      const float* __restrict__ wc = Wclf + (size_t)c * NRES + b;
      #pragma unroll 4
      for (int q = 0; q < 32; ++q) {
        const int W = 2 * q + (b >> 5);
        const unsigned mw =
            sm.maskg[(w >> 2) * MGP + (W >> 4) * 72 + (W & 15) * 4 + (w & 3)];
        const float wv = wc[q * 64];
        const unsigned keep =
            (unsigned)(((int)(mw << (31 - (b & 31)))) >> 31);
        pc += (double)__uint_as_float(keep & __float_as_uint(wv));
      }
      #pragma unroll
      for (int off = 1; off < 64; off <<= 1)
        pc += __shfl_xor(pc, off, 64);
      if (b == 0) sm.clfred2[0][c] = pc;
    }
  }
  __syncthreads();
  // E4: final classifier LIF (s(499)) + output
  if (w < B_ && tid < NCLS) {
    vc = 0.9 * vc + sm.clfred2[0][tid];
    if (vc >= 1.0) cntc++;
    out[w * NCLS + tid] = (float)cntc;
  }
  // E5: reservoir spike counts: lane b of wave il owns (bat b, neuron iu)
  out[B_ * NCLS + (size_t)b * NRES + w * SL + il] = (float)cntr;
}

extern "C" void kernel_launch(void* const* d_in, const int* in_sizes, int n_in,
                              void* d_out, int out_size, void* d_ws, size_t ws_size,
                              hipStream_t stream) {
  const float* x    = (const float*)d_in[0];   // (B, C, T)
  const float* Win  = (const float*)d_in[1];   // (NRES, C)
  const float* Wres = (const float*)d_in[2];   // (NRES, NRES)
  const float* Wclf = (const float*)d_in[3];   // (NCLS, NRES)
  float* out = (float*)d_out;
  unsigned char* ws = (unsigned char*)d_ws;

  hipLaunchKernelGGL(zero_ws_kernel, dim3((WS_WORDS + 255) / 256), dim3(256), 0, stream,
                     (unsigned*)ws, WS_WORDS);
  hipLaunchKernelGGL(reservoir_kernel, dim3(NWG), dim3(NT), 0, stream,
                     x, Win, Wres, Wclf, out, ws);
}